// Round 1
// baseline (399.218 us; speedup 1.0000x reference)
//
#include <hip/hip_runtime.h>

#define NPTS 1024
#define NC 256
#define NH 360
#define NW 360
#define NHW (NH * NW)
#define NCHW (NC * NHW)
#define PPB 8  // points per block in projection kernel

// Kernel 1: gather + 3-layer MLP for 2048 points (1024 from idx1, 1024 from idx2).
// Writes pq[2048][32]: rows 0..1023 = f1 @ w3 (p1), rows 1024..2047 = b3 - f2 @ w3 (q2).
__global__ __launch_bounds__(256) void project_kernel(
    const float* __restrict__ feature,
    const int* __restrict__ idx1,
    const int* __restrict__ idx2,
    const float* __restrict__ w1, const float* __restrict__ b1,
    const float* __restrict__ w2, const float* __restrict__ b2,
    const float* __restrict__ w3, const float* __restrict__ b3,
    float* __restrict__ pq)
{
    __shared__ float Xs[PPB * 256];   // gathered inputs
    __shared__ float H1s[PPB * 256];  // layer-1 activations
    __shared__ float F2s[PPB * 128];  // layer-2 activations

    const int tid = threadIdx.x;
    const int base = blockIdx.x * PPB;

    // ---- gather: X[p][c] = feature[b, c, h, w]  (stride NHW over c) ----
    #pragma unroll
    for (int p = 0; p < PPB; ++p) {
        int point = base + p;
        int col = (point < NPTS) ? point : (point - NPTS);
        const int* idx = (point < NPTS) ? idx1 : idx2;
        int bb = idx[col];
        int hh = idx[NPTS + col];
        int ww = idx[2 * NPTS + col];
        Xs[p * 256 + tid] =
            feature[(size_t)bb * NCHW + (size_t)tid * NHW + hh * NW + ww];
    }
    __syncthreads();

    // ---- layer 1: H1[p][j] = relu(sum_c X[p][c] * w1[c][j] + b1[j]), j = tid ----
    {
        float acc[PPB];
        #pragma unroll
        for (int p = 0; p < PPB; ++p) acc[p] = 0.f;
        #pragma unroll 4
        for (int c = 0; c < 256; ++c) {
            float wv = w1[c * 256 + tid];   // coalesced across threads
            #pragma unroll
            for (int p = 0; p < PPB; ++p)
                acc[p] = fmaf(Xs[p * 256 + c], wv, acc[p]);  // LDS broadcast
        }
        float bv = b1[tid];
        #pragma unroll
        for (int p = 0; p < PPB; ++p)
            H1s[p * 256 + tid] = fmaxf(acc[p] + bv, 0.f);
    }
    __syncthreads();

    // ---- layer 2: F2[p][j] = relu(sum_c H1[p][c] * w2[c][j] + b2[j]) ----
    // 256 threads: j = tid & 127, each thread covers 4 of the 8 points.
    {
        const int j = tid & 127;
        const int half = tid >> 7;   // 0 or 1
        float acc[4];
        #pragma unroll
        for (int q = 0; q < 4; ++q) acc[q] = 0.f;
        #pragma unroll 4
        for (int c = 0; c < 256; ++c) {
            float wv = w2[c * 128 + j];
            #pragma unroll
            for (int q = 0; q < 4; ++q)
                acc[q] = fmaf(H1s[(half * 4 + q) * 256 + c], wv, acc[q]);
        }
        float bv = b2[j];
        #pragma unroll
        for (int q = 0; q < 4; ++q)
            F2s[(half * 4 + q) * 128 + j] = fmaxf(acc[q] + bv, 0.f);
    }
    __syncthreads();

    // ---- layer 3: p[g][j] = sum_c F2[g][c] * w3[c][j]; j = tid&31, g = tid>>5 ----
    {
        const int j = tid & 31;
        const int g = tid >> 5;      // 0..7 -> point within block
        float acc = 0.f;
        #pragma unroll 4
        for (int c = 0; c < 128; ++c)
            acc = fmaf(F2s[g * 128 + c], w3[c * 32 + j], acc);
        int point = base + g;
        float val = (point < NPTS) ? acc : (b3[j] - acc);
        pq[(size_t)point * 32 + j] = val;   // 256 consecutive floats: coalesced
    }
}

// Kernel 2: out[m][n] = b4 + sum_k w4[k] * relu(p1[m][k] + q2[n][k])
// Grid: (1024/256 n-tiles, 1024/16 m-tiles), 256 threads (one n each, 16 m's).
__global__ __launch_bounds__(256) void pair_kernel(
    const float* __restrict__ pq,
    const float* __restrict__ w4,
    const float* __restrict__ b4,
    float* __restrict__ out)
{
    __shared__ float P1s[16 * 32];
    __shared__ float w4s[32];

    const int tid = threadIdx.x;
    const int n = blockIdx.x * 256 + tid;
    const int m0 = blockIdx.y * 16;

    // q2 row for this thread's n: 32 VGPRs
    float q[32];
    const float* q2 = pq + (size_t)(NPTS + n) * 32;
    #pragma unroll
    for (int k = 0; k < 32; ++k) q[k] = q2[k];

    // p1 tile (16 rows x 32) is contiguous: pq[m0*32 .. m0*32+512)
    for (int i = tid; i < 16 * 32; i += 256) P1s[i] = pq[(size_t)m0 * 32 + i];
    if (tid < 32) w4s[tid] = w4[tid];
    __syncthreads();

    const float b4v = b4[0];
    #pragma unroll 2
    for (int mm = 0; mm < 16; ++mm) {
        float acc = b4v;
        #pragma unroll
        for (int k = 0; k < 32; ++k) {
            float t = P1s[mm * 32 + k] + q[k];       // LDS broadcast + VGPR
            acc = fmaf(w4s[k], fmaxf(t, 0.f), acc);
        }
        out[(size_t)(m0 + mm) * 1024 + n] = acc;     // coalesced over n
    }
}

extern "C" void kernel_launch(void* const* d_in, const int* in_sizes, int n_in,
                              void* d_out, int out_size, void* d_ws, size_t ws_size,
                              hipStream_t stream) {
    const float* feature = (const float*)d_in[0];
    const int*   idx1    = (const int*)d_in[1];
    const int*   idx2    = (const int*)d_in[2];
    const float* w1      = (const float*)d_in[3];
    const float* b1      = (const float*)d_in[4];
    const float* w2      = (const float*)d_in[5];
    const float* b2      = (const float*)d_in[6];
    const float* w3      = (const float*)d_in[7];
    const float* b3      = (const float*)d_in[8];
    const float* w4      = (const float*)d_in[9];
    const float* b4      = (const float*)d_in[10];
    float* out = (float*)d_out;

    float* pq = (float*)d_ws;  // 2048 * 32 floats = 256 KB

    project_kernel<<<2048 / PPB, 256, 0, stream>>>(
        feature, idx1, idx2, w1, b1, w2, b2, w3, b3, pq);

    pair_kernel<<<dim3(1024 / 256, 1024 / 16), 256, 0, stream>>>(
        pq, w4, b4, out);
}